// Round 17
// baseline (33.989 us; speedup 1.0000x reference)
//
#include <hip/hip_runtime.h>
#include <stdint.h>

// Problem constants (from reference)
#define N_AG   8
#define S_SAMP 16
#define TB     8192      // T*B
#define DST    128       // D_STATE
#define E_DIM  64

#define RPB    16        // rows per block -> 512 blocks, 512 threads (8 waves)
#define CN_STR 9         // cn stride: spreads 16 samples over banks

// WT layout in d_ws (bf16 element offsets): [n][k] row-major, k-stride 128
#define WT1K1  0         // hw1_k1^T  [128][128]
#define WT2K1  16384     // hw2_k1^T  [128][128]
#define WT1K2  32768     // hw1_k2^T  [128][128]
#define WTM3   49152     // rows 0..63 = b1_k^T, rows 64..127 = hb2_k1^T
#define WT2K2  65536     // hw2_k2^T  [64][128]
#define WT_ELEMS 73728   // total bf16 elements (147456 B)

typedef __attribute__((ext_vector_type(8))) short  short8v;   // 8 bf16 = 4 VGPR
typedef __attribute__((ext_vector_type(4))) float  float4v;   // C/D frag

__device__ __forceinline__ float4 ld4(const float* p) { return *(const float4*)p; }

// f32 -> bf16 round-to-nearest-even
__device__ __forceinline__ unsigned short f2bf(float f) {
  uint32_t x = __float_as_uint(f);
  return (unsigned short)((x + 0x7FFFu + ((x >> 16) & 1u)) >> 16);
}
__device__ __forceinline__ uint32_t pk2(float lo, float hi) {
  return (uint32_t)f2bf(lo) | ((uint32_t)f2bf(hi) << 16);
}

// ---------------- JAX threefry2x32 (20 rounds) ----------------
__device__ __forceinline__ uint2 tf2x32(uint32_t k0, uint32_t k1,
                                        uint32_t c0, uint32_t c1) {
  uint32_t ks2 = k0 ^ k1 ^ 0x1BD11BDAu;
  uint32_t x0 = c0 + k0, x1 = c1 + k1;
#define TFR(r) { x0 += x1; x1 = (x1 << (r)) | (x1 >> (32 - (r))); x1 ^= x0; }
  TFR(13) TFR(15) TFR(26) TFR(6)
  x0 += k1;  x1 += ks2 + 1u;
  TFR(17) TFR(29) TFR(16) TFR(24)
  x0 += ks2; x1 += k0 + 2u;
  TFR(13) TFR(15) TFR(26) TFR(6)
  x0 += k0;  x1 += k1 + 3u;
  TFR(17) TFR(29) TFR(16) TFR(24)
  x0 += k1;  x1 += ks2 + 4u;
  TFR(13) TFR(15) TFR(26) TFR(6)
  x0 += ks2; x1 += k0 + 5u;
#undef TFR
  return make_uint2(x0, x1);
}

// Swizzled bf16 LDS tile helpers (R9-verified): rows 256B, byte ^= (row&7)<<4
__device__ __forceinline__ short8v rdfrag(const unsigned short* base, int row, int ks, int lhi) {
  const int b = (row * 256 + ks * 64 + lhi * 16) ^ ((row & 7) << 4);
  return *(const short8v*)((const char*)base + b);
}
__device__ __forceinline__ void wrbf(unsigned short* pan, int r, int c, float v) {
  const int b = (r * 256 + c * 2) ^ ((r & 7) << 4);
  *(unsigned short*)((char*)pan + b) = f2bf(v);
}
// B-fragment directly from global pre-transposed bf16 (R10-verified)
__device__ __forceinline__ short8v gfrag(const unsigned short* wt, int n, int ks, int lhi) {
  return *(const short8v*)(wt + (n << 7) + ks * 32 + lhi * 8);
}

// ========== K0: transpose+convert all weights to bf16 [n][k] in d_ws (R10-verified) ==========
__global__ __launch_bounds__(256)
void wt_transpose(const float* __restrict__ hw1_k1, const float* __restrict__ hw2_k1,
                  const float* __restrict__ hw1_k2, const float* __restrict__ b1_k,
                  const float* __restrict__ hb2_k1, const float* __restrict__ hw2_k2,
                  unsigned short* __restrict__ wt)
{
  __shared__ float t[32][33];
  const int b = blockIdx.x;
  const float* src; int ldn, t0, dstbase;
  if (b < 16)      { src = hw1_k1; ldn = 128; t0 = b;      dstbase = WT1K1; }
  else if (b < 32) { src = hw2_k1; ldn = 128; t0 = b - 16; dstbase = WT2K1; }
  else if (b < 48) { src = hw1_k2; ldn = 128; t0 = b - 32; dstbase = WT1K2; }
  else if (b < 56) { src = b1_k;   ldn = 64;  t0 = b - 48; dstbase = WTM3; }
  else if (b < 64) { src = hb2_k1; ldn = 64;  t0 = b - 56; dstbase = WTM3 + 64 * 128; }
  else             { src = hw2_k2; ldn = 64;  t0 = b - 64; dstbase = WT2K2; }
  const int kt = t0 & 3, nt = t0 >> 2;
  const int tid = threadIdx.x;
  {
    const int c = tid & 31;
    for (int r = tid >> 5; r < 32; r += 8)
      t[r][c] = src[(size_t)(kt * 32 + r) * ldn + nt * 32 + c];
  }
  __syncthreads();
  {
    const int c2 = tid & 15;
    for (int n = tid >> 4; n < 32; n += 16) {
      const uint32_t v = pk2(t[2 * c2][n], t[2 * c2 + 1][n]);
      *(uint32_t*)&wt[dstbase + (nt * 32 + n) * 128 + kt * 32 + 2 * c2] = v;
    }
  }
}

// ========================= Main fused kernel =========================
// R15/R16-verified structure (RPB=16, 512 threads, full M=16 tiles, balanced
// RNG, M5 on waves 4-7). R17 change: M4's four B-fragments are prefetched
// into registers BEFORE the mid-barrier (wt is immutable -> timing-only
// hoist; no numerics or sync-surface change).
__global__ __launch_bounds__(512, 4)
void alpha_mfma3(const float* __restrict__ q_vals,   // (8, 8192)
                 const float* __restrict__ states,   // (8192, 128)
                 const float* __restrict__ hw1_b1, const float* __restrict__ hw1_b2,
                 const float* __restrict__ b1_b,   const float* __restrict__ hw2_b1,
                 const float* __restrict__ hw2_b2, const float* __restrict__ hb2_b1,
                 const float* __restrict__ hb2_k2, const float* __restrict__ hb2_b2,
                 const unsigned short* __restrict__ wt,
                 float* __restrict__ out)            // (8, 8192)
{
  __shared__ unsigned short xbf[RPB * 128];     // X bf16 swz            4 KB
  __shared__ unsigned short h1bf[RPB * 128];    // relu(h1) bf16 swz     4 KB
  __shared__ unsigned short h2bf[RPB * 128];    // relu(h2) bf16 swz     4 KB
  __shared__ float w1l[RPB][132];               // |w1| f32            8.4 KB
  __shared__ float b1l[RPB][68];                //                     4.3 KB
  __shared__ float w2l[RPB][68];                //                     4.3 KB
  __shared__ float hbl[RPB][68];                //                     4.3 KB
  __shared__ float b2l[RPB];
  __shared__ float ql[RPB][N_AG];
  __shared__ float cn_l[RPB][S_SAMP][CN_STR];   // cn then |y|         9.2 KB

  const int tid  = threadIdx.x;
  const int row0 = blockIdx.x * RPB;
  const int lane = tid & 63;
  const int wv   = tid >> 6;        // wave 0..7
  const int lrow = lane & 15;       // A-row / B-col within a 16-tile
  const int lhi  = lane >> 4;       // k-group; C rows lhi*4+j (ALL 16 used)

  // ---- P0: X f32 -> bf16 swz LDS (16 rows, 512 float4 = 1/thread); q load ----
  {
    const int r = tid >> 5, k0 = (tid & 31) * 4;
    const float4 v = ld4(&states[(size_t)(row0 + r) * DST + k0]);
    const int b = (r * 256 + k0 * 2) ^ ((r & 7) << 4);
    *(uint32_t*)((char*)xbf + b)     = pk2(v.x, v.y);
    *(uint32_t*)((char*)xbf + b + 4) = pk2(v.z, v.w);
  }
  if (tid < RPB * N_AG) {
    const int rr = tid >> 3, a = tid & 7;
    ql[rr][a] = q_vals[a * TB + row0 + rr];
  }
  __syncthreads();

  // ---- RNG: one (row, sample) per thread, tid<256 = waves 0-3 (verified chain) ----
  if (tid < RPB * S_SAMP) {
    const int r  = tid >> 4;
    const int sl = tid & 15;
    const uint32_t j = (uint32_t)(row0 + r) * (uint32_t)S_SAMP + (uint32_t)sl;
    uint2 kj  = tf2x32(0u, 42u, 0u, j);       // partitionable split of key(42)
    uint2 sub = tf2x32(kj.x, kj.y, 0u, 1u);   // subkey = split(key_j)[1]
    uint32_t K[N_AG];
#pragma unroll
    for (int i = 0; i < N_AG; ++i) {
      uint2 b = tf2x32(sub.x, sub.y, 0u, (uint32_t)i);
      K[i] = b.x ^ b.y;
    }
    int posa[N_AG];
#pragma unroll
    for (int i = 0; i < N_AG; ++i) {
      int rank = 0;
#pragma unroll
      for (int m = 0; m < N_AG; ++m)
        rank += (K[m] < K[i]) || (K[m] == K[i] && m < i);
      posa[rank] = i;
    }
#pragma unroll
    for (int a = 0; a < N_AG; ++a) {
      const int pa = posa[a];
      float cs = 0.f;
#pragma unroll
      for (int a2 = 0; a2 < N_AG; ++a2)
        cs += (posa[a2] < pa) ? ql[r][a2] : 0.f;
      cn_l[r][sl][a] = cs / (float)max(pa, 1);
    }
  }

  // ===== M1: h1 = relu(X @ hw1_k1 + b) -> h1bf  (8 waves x 16 cols) =====
  {
    float4v a0 = {0.f,0.f,0.f,0.f};
    const int c = wv * 16 + lrow;
#pragma unroll
    for (int ks = 0; ks < 4; ++ks) {
      const short8v af = rdfrag(xbf, lrow, ks, lhi);
      a0 = __builtin_amdgcn_mfma_f32_16x16x32_bf16(af, gfrag(wt + WT1K1, c, ks, lhi), a0, 0, 0, 0);
    }
    const float bv = hw1_b1[c];
#pragma unroll
    for (int j = 0; j < 4; ++j)
      wrbf(h1bf, lhi * 4 + j, c, fmaxf(a0[j] + bv, 0.f));
  }

  // ===== M2: h2 = relu(X @ hw2_k1 + b) -> h2bf =====
  {
    float4v a0 = {0.f,0.f,0.f,0.f};
    const int c = wv * 16 + lrow;
#pragma unroll
    for (int ks = 0; ks < 4; ++ks) {
      const short8v af = rdfrag(xbf, lrow, ks, lhi);
      a0 = __builtin_amdgcn_mfma_f32_16x16x32_bf16(af, gfrag(wt + WT2K1, c, ks, lhi), a0, 0, 0, 0);
    }
    const float bv = hw2_b1[c];
#pragma unroll
    for (int j = 0; j < 4; ++j)
      wrbf(h2bf, lhi * 4 + j, c, fmaxf(a0[j] + bv, 0.f));
  }

  // ===== M3: cols 0..63 -> b1 = X@b1_k + b; 64..127 -> hb = relu(X@hb2_k1 + b) =====
  {
    float4v a0 = {0.f,0.f,0.f,0.f};
    const int c = wv * 16 + lrow;
#pragma unroll
    for (int ks = 0; ks < 4; ++ks) {
      const short8v af = rdfrag(xbf, lrow, ks, lhi);
      a0 = __builtin_amdgcn_mfma_f32_16x16x32_bf16(af, gfrag(wt + WTM3, c, ks, lhi), a0, 0, 0, 0);
    }
    if (c < 64) {
      const float bv = b1_b[c];
#pragma unroll
      for (int j = 0; j < 4; ++j)
        b1l[lhi * 4 + j][c] = a0[j] + bv;
    } else {
      const float bv = hb2_b1[c - 64];
#pragma unroll
      for (int j = 0; j < 4; ++j)
        hbl[lhi * 4 + j][c - 64] = fmaxf(a0[j] + bv, 0.f);
    }
  }

  // ---- R17: prefetch M4's B-fragments across the barrier (wt is read-only;
  //      named variables -> registers, no runtime indexing) ----
  short8v pw4_0, pw4_1, pw4_2, pw4_3;
  {
    const int c = wv * 16 + lrow;
    pw4_0 = gfrag(wt + WT1K2, c, 0, lhi);
    pw4_1 = gfrag(wt + WT1K2, c, 1, lhi);
    pw4_2 = gfrag(wt + WT1K2, c, 2, lhi);
    pw4_3 = gfrag(wt + WT1K2, c, 3, lhi);
  }
  __syncthreads();   // h1bf/h2bf/b1l/hbl/cn_l now visible

  // ---- b2[r] (waves 0-3) ----
  if (tid < RPB * S_SAMP) {
    const int r = tid >> 4, sl = tid & 15;
    float v = hbl[r][sl]      * hb2_k2[sl]
            + hbl[r][sl + 16] * hb2_k2[sl + 16]
            + hbl[r][sl + 32] * hb2_k2[sl + 32]
            + hbl[r][sl + 48] * hb2_k2[sl + 48];
    v += __shfl_down(v, 8, 16); v += __shfl_down(v, 4, 16);
    v += __shfl_down(v, 2, 16); v += __shfl_down(v, 1, 16);
    if (sl == 0) b2l[r] = v + hb2_b2[0];
  }

  // ===== M5: w2 = |h2 @ hw2_k2 + b| (waves 4-7; balanced vs b2 on 0-3) =====
  if (wv >= 4) {
    float4v a0 = {0.f,0.f,0.f,0.f};
    const int c = (wv - 4) * 16 + lrow;
#pragma unroll
    for (int ks = 0; ks < 4; ++ks) {
      const short8v af = rdfrag(h2bf, lrow, ks, lhi);
      a0 = __builtin_amdgcn_mfma_f32_16x16x32_bf16(af, gfrag(wt + WT2K2, c, ks, lhi), a0, 0, 0, 0);
    }
    const float bv = hw2_b2[c];
#pragma unroll
    for (int j = 0; j < 4; ++j)
      w2l[lhi * 4 + j][c] = fabsf(a0[j] + bv);
  }

  // ===== M4: w1 = |h1 @ hw1_k2 + b| -> w1l (f32), all waves; uses prefetched frags =====
  {
    float4v a0 = {0.f,0.f,0.f,0.f};
    const int c = wv * 16 + lrow;
    a0 = __builtin_amdgcn_mfma_f32_16x16x32_bf16(rdfrag(h1bf, lrow, 0, lhi), pw4_0, a0, 0, 0, 0);
    a0 = __builtin_amdgcn_mfma_f32_16x16x32_bf16(rdfrag(h1bf, lrow, 1, lhi), pw4_1, a0, 0, 0, 0);
    a0 = __builtin_amdgcn_mfma_f32_16x16x32_bf16(rdfrag(h1bf, lrow, 2, lhi), pw4_2, a0, 0, 0, 0);
    a0 = __builtin_amdgcn_mfma_f32_16x16x32_bf16(rdfrag(h1bf, lrow, 3, lhi), pw4_3, a0, 0, 0, 0);
    const float bv = hw1_b2[c];
#pragma unroll
    for (int j = 0; j < 4; ++j)
      w1l[lhi * 4 + j][c] = fabsf(a0[j] + bv);
  }
  __syncthreads();   // w1l/w2l/b2l visible

  // ===== Main: thread = (r in 16, sl in 16, agent-half in 2); all 512 active =====
  {
    const int sl  = tid & 15;
    const int r   = (tid >> 4) & 15;
    const int a0i = (tid >> 8) * 4;   // agents a0i..a0i+3
    float cn[4], qv[4], y[4];
#pragma unroll
    for (int jj = 0; jj < 4; ++jj) {
      cn[jj] = cn_l[r][sl][a0i + jj];
      qv[jj] = ql[r][a0i + jj];
      y[jj]  = 0.f;
    }
#pragma unroll 4
    for (int e = 0; e < E_DIM; e += 4) {
      const float4 wa  = ld4(&w1l[r][e]);
      const float4 wb  = ld4(&w1l[r][64 + e]);
      const float4 bb  = ld4(&b1l[r][e]);
      const float4 w2v = ld4(&w2l[r][e]);
#pragma unroll
      for (int jj = 0; jj < 4; ++jj) {
        float h;
        h = fmaf(cn[jj], wa.x, fmaf(qv[jj], wb.x, bb.x));
        y[jj] = fmaf((h > 0.f) ? h : (__expf(h) - 1.f), w2v.x, y[jj]);
        h = fmaf(cn[jj], wa.y, fmaf(qv[jj], wb.y, bb.y));
        y[jj] = fmaf((h > 0.f) ? h : (__expf(h) - 1.f), w2v.y, y[jj]);
        h = fmaf(cn[jj], wa.z, fmaf(qv[jj], wb.z, bb.z));
        y[jj] = fmaf((h > 0.f) ? h : (__expf(h) - 1.f), w2v.z, y[jj]);
        h = fmaf(cn[jj], wa.w, fmaf(qv[jj], wb.w, bb.w));
        y[jj] = fmaf((h > 0.f) ? h : (__expf(h) - 1.f), w2v.w, y[jj]);
      }
    }
    const float b2v = b2l[r];
#pragma unroll
    for (int jj = 0; jj < 4; ++jj)
      cn_l[r][sl][a0i + jj] = fabsf(y[jj] + b2v);   // own slots only
  }
  __syncthreads();

  // ---- Reduce over samples; rr = tid&15 so 16 consecutive rows coalesce ----
  if (tid < RPB * N_AG) {
    const int rr = tid & 15, a = tid >> 4;
    float acc = 0.f;
#pragma unroll
    for (int ss = 0; ss < S_SAMP; ++ss) acc += cn_l[rr][ss][a];
    out[a * TB + row0 + rr] = acc * (1.0f / (float)S_SAMP);
  }
}

// ============ Fallback (R4-structure, proven): used only if ws too small ============
#define FB_RPB 16
#define FB_H_PAD 132
#define FB_E_PAD 68
__global__ __launch_bounds__(256)
void alpha_fused2(const float* __restrict__ q_vals, const float* __restrict__ states,
                  const float* __restrict__ hw1_k1, const float* __restrict__ hw1_b1,
                  const float* __restrict__ hw1_k2, const float* __restrict__ hw1_b2,
                  const float* __restrict__ b1_k,   const float* __restrict__ b1_b,
                  const float* __restrict__ hw2_k1, const float* __restrict__ hw2_b1,
                  const float* __restrict__ hw2_k2, const float* __restrict__ hw2_b2,
                  const float* __restrict__ hb2_k1, const float* __restrict__ hb2_b1,
                  const float* __restrict__ hb2_k2, const float* __restrict__ hb2_b2,
                  float* __restrict__ out)
{
  __shared__ float s_lds[FB_RPB][DST];
  __shared__ float scratch[FB_RPB][FB_H_PAD];
  __shared__ float scratch2[FB_RPB][FB_E_PAD];
  __shared__ float w1l[FB_RPB][FB_H_PAD];
  __shared__ float b1l[FB_RPB][FB_E_PAD];
  __shared__ float w2l[FB_RPB][FB_E_PAD];
  __shared__ float b2l[FB_RPB];
  __shared__ float qlf[FB_RPB][N_AG];
  __shared__ float cnred[FB_RPB][S_SAMP][N_AG];
  const int tid = threadIdx.x;
  const int row0 = blockIdx.x * FB_RPB;
  const int r = tid >> 4, sl = tid & 15;
  {
    const float4* src = reinterpret_cast<const float4*>(states + (size_t)row0 * DST);
    reinterpret_cast<float4*>(&s_lds[0][0])[tid]       = src[tid];
    reinterpret_cast<float4*>(&s_lds[0][0])[tid + 256] = src[tid + 256];
  }
  if (tid < FB_RPB * N_AG) {
    const int rr = tid >> 3, a = tid & 7;
    qlf[rr][a] = q_vals[a * TB + row0 + rr];
  }
  __syncthreads();
  {
    const uint32_t j = (uint32_t)(row0 + r) * (uint32_t)S_SAMP + (uint32_t)sl;
    uint2 kj = tf2x32(0u, 42u, 0u, j);
    uint2 sub = tf2x32(kj.x, kj.y, 0u, 1u);
    uint32_t K[N_AG];
#pragma unroll
    for (int i = 0; i < N_AG; ++i) { uint2 b = tf2x32(sub.x, sub.y, 0u, (uint32_t)i); K[i] = b.x ^ b.y; }
    int posa[N_AG];
#pragma unroll
    for (int i = 0; i < N_AG; ++i) {
      int rank = 0;
#pragma unroll
      for (int m = 0; m < N_AG; ++m) rank += (K[m] < K[i]) || (K[m] == K[i] && m < i);
      posa[rank] = i;
    }
#pragma unroll
    for (int a = 0; a < N_AG; ++a) {
      const int pa = posa[a];
      float cs = 0.f;
#pragma unroll
      for (int a2 = 0; a2 < N_AG; ++a2) cs += (posa[a2] < pa) ? qlf[r][a2] : 0.f;
      cnred[r][sl][a] = cs / (float)max(pa, 1);
    }
  }
  {
    int c = tid & 127, rg = tid >> 7;
    float a0=0.f,a1=0.f,a2=0.f,a3=0.f,a4=0.f,a5=0.f,a6=0.f,a7=0.f;
#pragma unroll 2
    for (int k = 0; k < DST; ++k) {
      float wv = hw1_k1[k * 128 + c];
      a0 += s_lds[rg*8+0][k]*wv; a1 += s_lds[rg*8+1][k]*wv;
      a2 += s_lds[rg*8+2][k]*wv; a3 += s_lds[rg*8+3][k]*wv;
      a4 += s_lds[rg*8+4][k]*wv; a5 += s_lds[rg*8+5][k]*wv;
      a6 += s_lds[rg*8+6][k]*wv; a7 += s_lds[rg*8+7][k]*wv;
    }
    float b = hw1_b1[c];
    scratch[rg*8+0][c]=fmaxf(a0+b,0.f); scratch[rg*8+1][c]=fmaxf(a1+b,0.f);
    scratch[rg*8+2][c]=fmaxf(a2+b,0.f); scratch[rg*8+3][c]=fmaxf(a3+b,0.f);
    scratch[rg*8+4][c]=fmaxf(a4+b,0.f); scratch[rg*8+5][c]=fmaxf(a5+b,0.f);
    scratch[rg*8+6][c]=fmaxf(a6+b,0.f); scratch[rg*8+7][c]=fmaxf(a7+b,0.f);
  }
  {
    int c = tid & 63, rg = tid >> 6;
    float a0=0.f,a1=0.f,a2=0.f,a3=0.f;
#pragma unroll 2
    for (int k = 0; k < DST; ++k) {
      float wv = b1_k[k * 64 + c];
      a0 += s_lds[rg*4+0][k]*wv; a1 += s_lds[rg*4+1][k]*wv;
      a2 += s_lds[rg*4+2][k]*wv; a3 += s_lds[rg*4+3][k]*wv;
    }
    float b = b1_b[c];
    b1l[rg*4+0][c]=a0+b; b1l[rg*4+1][c]=a1+b; b1l[rg*4+2][c]=a2+b; b1l[rg*4+3][c]=a3+b;
  }
  __syncthreads();
  {
    int c = tid & 127, rg = tid >> 7;
    float a0=0.f,a1=0.f,a2=0.f,a3=0.f,a4=0.f,a5=0.f,a6=0.f,a7=0.f;
#pragma unroll 2
    for (int k = 0; k < DST; ++k) {
      float wv = hw1_k2[k * 128 + c];
      a0 += scratch[rg*8+0][k]*wv; a1 += scratch[rg*8+1][k]*wv;
      a2 += scratch[rg*8+2][k]*wv; a3 += scratch[rg*8+3][k]*wv;
      a4 += scratch[rg*8+4][k]*wv; a5 += scratch[rg*8+5][k]*wv;
      a6 += scratch[rg*8+6][k]*wv; a7 += scratch[rg*8+7][k]*wv;
    }
    float b = hw1_b2[c];
    w1l[rg*8+0][c]=fabsf(a0+b); w1l[rg*8+1][c]=fabsf(a1+b);
    w1l[rg*8+2][c]=fabsf(a2+b); w1l[rg*8+3][c]=fabsf(a3+b);
    w1l[rg*8+4][c]=fabsf(a4+b); w1l[rg*8+5][c]=fabsf(a5+b);
    w1l[rg*8+6][c]=fabsf(a6+b); w1l[rg*8+7][c]=fabsf(a7+b);
  }
  {
    int c = tid & 63, rg = tid >> 6;
    float a0=0.f,a1=0.f,a2=0.f,a3=0.f;
#pragma unroll 2
    for (int k = 0; k < DST; ++k) {
      float wv = hb2_k1[k * 64 + c];
      a0 += s_lds[rg*4+0][k]*wv; a1 += s_lds[rg*4+1][k]*wv;
      a2 += s_lds[rg*4+2][k]*wv; a3 += s_lds[rg*4+3][k]*wv;
    }
    float b = hb2_b1[c];
    scratch2[rg*4+0][c]=fmaxf(a0+b,0.f); scratch2[rg*4+1][c]=fmaxf(a1+b,0.f);
    scratch2[rg*4+2][c]=fmaxf(a2+b,0.f); scratch2[rg*4+3][c]=fmaxf(a3+b,0.f);
  }
  __syncthreads();
  {
    int c = tid & 127, rg = tid >> 7;
    float a0=0.f,a1=0.f,a2=0.f,a3=0.f,a4=0.f,a5=0.f,a6=0.f,a7=0.f;
#pragma unroll 2
    for (int k = 0; k < DST; ++k) {
      float wv = hw2_k1[k * 128 + c];
      a0 += s_lds[rg*8+0][k]*wv; a1 += s_lds[rg*8+1][k]*wv;
      a2 += s_lds[rg*8+2][k]*wv; a3 += s_lds[rg*8+3][k]*wv;
      a4 += s_lds[rg*8+4][k]*wv; a5 += s_lds[rg*8+5][k]*wv;
      a6 += s_lds[rg*8+6][k]*wv; a7 += s_lds[rg*8+7][k]*wv;
    }
    float b = hw2_b1[c];
    scratch[rg*8+0][c]=fmaxf(a0+b,0.f); scratch[rg*8+1][c]=fmaxf(a1+b,0.f);
    scratch[rg*8+2][c]=fmaxf(a2+b,0.f); scratch[rg*8+3][c]=fmaxf(a3+b,0.f);
    scratch[rg*8+4][c]=fmaxf(a4+b,0.f); scratch[rg*8+5][c]=fmaxf(a5+b,0.f);
    scratch[rg*8+6][c]=fmaxf(a6+b,0.f); scratch[rg*8+7][c]=fmaxf(a7+b,0.f);
  }
  if (tid < FB_RPB * S_SAMP) {
    float v = scratch2[r][sl]      * hb2_k2[sl]
            + scratch2[r][sl + 16] * hb2_k2[sl + 16]
            + scratch2[r][sl + 32] * hb2_k2[sl + 32]
            + scratch2[r][sl + 48] * hb2_k2[sl + 48];
    v += __shfl_down(v, 8, 16); v += __shfl_down(v, 4, 16);
    v += __shfl_down(v, 2, 16); v += __shfl_down(v, 1, 16);
    if (sl == 0) b2l[r] = v + hb2_b2[0];
  }
  __syncthreads();
  {
    int c = tid & 63, rg = tid >> 6;
    float a0=0.f,a1=0.f,a2=0.f,a3=0.f;
#pragma unroll 2
    for (int k = 0; k < DST; ++k) {
      float wv = hw2_k2[k * 64 + c];
      a0 += scratch[rg*4+0][k]*wv; a1 += scratch[rg*4+1][k]*wv;
      a2 += scratch[rg*4+2][k]*wv; a3 += scratch[rg*4+3][k]*wv;
    }
    float b = hw2_b2[c];
    w2l[rg*4+0][c]=fabsf(a0+b); w2l[rg*4+1][c]=fabsf(a1+b);
    w2l[rg*4+2][c]=fabsf(a2+b); w2l[rg*4+3][c]=fabsf(a3+b);
  }
  __syncthreads();
  {
    float cn[N_AG], qv[N_AG], y[N_AG];
#pragma unroll
    for (int a = 0; a < N_AG; ++a) { cn[a]=cnred[r][sl][a]; qv[a]=qlf[r][a]; y[a]=0.f; }
#pragma unroll 4
    for (int e = 0; e < E_DIM; e += 4) {
      const float4 wa  = ld4(&w1l[r][e]);
      const float4 wb  = ld4(&w1l[r][64 + e]);
      const float4 bb  = ld4(&b1l[r][e]);
      const float4 w2v = ld4(&w2l[r][e]);
#pragma unroll
      for (int a = 0; a < N_AG; ++a) {
        float h;
        h = fmaf(cn[a], wa.x, fmaf(qv[a], wb.x, bb.x));
        y[a] = fmaf((h > 0.f) ? h : (__expf(h) - 1.f), w2v.x, y[a]);
        h = fmaf(cn[a], wa.y, fmaf(qv[a], wb.y, bb.y));
        y[a] = fmaf((h > 0.f) ? h : (__expf(h) - 1.f), w2v.y, y[a]);
        h = fmaf(cn[a], wa.z, fmaf(qv[a], wb.z, bb.z));
        y[a] = fmaf((h > 0.f) ? h : (__expf(h) - 1.f), w2v.z, y[a]);
        h = fmaf(cn[a], wa.w, fmaf(qv[a], wb.w, bb.w));
        y[a] = fmaf((h > 0.f) ? h : (__expf(h) - 1.f), w2v.w, y[a]);
      }
    }
    const float b2v = b2l[r];
#pragma unroll
    for (int a = 0; a < N_AG; ++a) cnred[r][sl][a] = fabsf(y[a] + b2v);
  }
  __syncthreads();
  if (tid < FB_RPB * N_AG) {
    const int a = tid >> 4, rr = tid & 15;
    float acc = 0.f;
#pragma unroll
    for (int ss = 0; ss < S_SAMP; ++ss) acc += cnred[rr][ss][a];
    out[a * TB + row0 + rr] = acc * (1.0f / (float)S_SAMP);
  }
}

extern "C" void kernel_launch(void* const* d_in, const int* in_sizes, int n_in,
                              void* d_out, int out_size, void* d_ws, size_t ws_size,
                              hipStream_t stream) {
  const float* q_vals = (const float*)d_in[0];
  const float* states = (const float*)d_in[1];
  const float* hw1_k1 = (const float*)d_in[2];
  const float* hw1_b1 = (const float*)d_in[3];
  const float* hw1_k2 = (const float*)d_in[4];
  const float* hw1_b2 = (const float*)d_in[5];
  const float* b1_k   = (const float*)d_in[6];
  const float* b1_b   = (const float*)d_in[7];
  const float* hw2_k1 = (const float*)d_in[8];
  const float* hw2_b1 = (const float*)d_in[9];
  const float* hw2_k2 = (const float*)d_in[10];
  const float* hw2_b2 = (const float*)d_in[11];
  const float* hb2_k1 = (const float*)d_in[12];
  const float* hb2_b1 = (const float*)d_in[13];
  const float* hb2_k2 = (const float*)d_in[14];
  const float* hb2_b2 = (const float*)d_in[15];
  float* out = (float*)d_out;

  const size_t need = (size_t)WT_ELEMS * sizeof(unsigned short);
  if (ws_size >= need) {
    unsigned short* wt = (unsigned short*)d_ws;
    wt_transpose<<<dim3(72), 256, 0, stream>>>(
        hw1_k1, hw2_k1, hw1_k2, b1_k, hb2_k1, hw2_k2, wt);
    alpha_mfma3<<<dim3(TB / RPB), 512, 0, stream>>>(
        q_vals, states, hw1_b1, hw1_b2, b1_b, hw2_b1, hw2_b2, hb2_b1,
        hb2_k2, hb2_b2, wt, out);
  } else {
    alpha_fused2<<<dim3(TB / FB_RPB), 256, 0, stream>>>(
        q_vals, states, hw1_k1, hw1_b1, hw1_k2, hw1_b2, b1_k, b1_b,
        hw2_k1, hw2_b1, hw2_k2, hw2_b2, hb2_k1, hb2_b1, hb2_k2, hb2_b2, out);
  }
}

// Round 18
// 33.422 us; speedup vs baseline: 1.0170x; 1.0170x over previous
//
#include <hip/hip_runtime.h>
#include <stdint.h>

// Problem constants (from reference)
#define N_AG   8
#define S_SAMP 16
#define TB     8192      // T*B
#define DST    128       // D_STATE
#define E_DIM  64

#define RPB    16        // rows per block -> 512 blocks, 512 threads (8 waves)
#define CN_STR 9         // cn stride: spreads 16 samples over banks

// WT layout in d_ws (bf16 element offsets): [n][k] row-major, k-stride 128
#define WT1K1  0         // hw1_k1^T  [128][128]
#define WT2K1  16384     // hw2_k1^T  [128][128]
#define WT1K2  32768     // hw1_k2^T  [128][128]
#define WTM3   49152     // rows 0..63 = b1_k^T, rows 64..127 = hb2_k1^T
#define WT2K2  65536     // hw2_k2^T  [64][128]
#define WT_ELEMS 73728   // total bf16 elements (147456 B)

typedef __attribute__((ext_vector_type(8))) short  short8v;   // 8 bf16 = 4 VGPR
typedef __attribute__((ext_vector_type(4))) float  float4v;   // C/D frag

__device__ __forceinline__ float4 ld4(const float* p) { return *(const float4*)p; }

// f32 -> bf16 round-to-nearest-even
__device__ __forceinline__ unsigned short f2bf(float f) {
  uint32_t x = __float_as_uint(f);
  return (unsigned short)((x + 0x7FFFu + ((x >> 16) & 1u)) >> 16);
}
__device__ __forceinline__ uint32_t pk2(float lo, float hi) {
  return (uint32_t)f2bf(lo) | ((uint32_t)f2bf(hi) << 16);
}

// ---------------- JAX threefry2x32 (20 rounds) ----------------
__device__ __forceinline__ uint2 tf2x32(uint32_t k0, uint32_t k1,
                                        uint32_t c0, uint32_t c1) {
  uint32_t ks2 = k0 ^ k1 ^ 0x1BD11BDAu;
  uint32_t x0 = c0 + k0, x1 = c1 + k1;
#define TFR(r) { x0 += x1; x1 = (x1 << (r)) | (x1 >> (32 - (r))); x1 ^= x0; }
  TFR(13) TFR(15) TFR(26) TFR(6)
  x0 += k1;  x1 += ks2 + 1u;
  TFR(17) TFR(29) TFR(16) TFR(24)
  x0 += ks2; x1 += k0 + 2u;
  TFR(13) TFR(15) TFR(26) TFR(6)
  x0 += k0;  x1 += k1 + 3u;
  TFR(17) TFR(29) TFR(16) TFR(24)
  x0 += k1;  x1 += ks2 + 4u;
  TFR(13) TFR(15) TFR(26) TFR(6)
  x0 += ks2; x1 += k0 + 5u;
#undef TFR
  return make_uint2(x0, x1);
}

// Swizzled bf16 LDS tile helpers (R9-verified): rows 256B, byte ^= (row&7)<<4
__device__ __forceinline__ short8v rdfrag(const unsigned short* base, int row, int ks, int lhi) {
  const int b = (row * 256 + ks * 64 + lhi * 16) ^ ((row & 7) << 4);
  return *(const short8v*)((const char*)base + b);
}
__device__ __forceinline__ void wrbf(unsigned short* pan, int r, int c, float v) {
  const int b = (r * 256 + c * 2) ^ ((r & 7) << 4);
  *(unsigned short*)((char*)pan + b) = f2bf(v);
}
// B-fragment directly from global pre-transposed bf16 (R10-verified)
__device__ __forceinline__ short8v gfrag(const unsigned short* wt, int n, int ks, int lhi) {
  return *(const short8v*)(wt + (n << 7) + ks * 32 + lhi * 8);
}

// ========== K0: transpose+convert all weights to bf16 [n][k] in d_ws (R10-verified) ==========
__global__ __launch_bounds__(256)
void wt_transpose(const float* __restrict__ hw1_k1, const float* __restrict__ hw2_k1,
                  const float* __restrict__ hw1_k2, const float* __restrict__ b1_k,
                  const float* __restrict__ hb2_k1, const float* __restrict__ hw2_k2,
                  unsigned short* __restrict__ wt)
{
  __shared__ float t[32][33];
  const int b = blockIdx.x;
  const float* src; int ldn, t0, dstbase;
  if (b < 16)      { src = hw1_k1; ldn = 128; t0 = b;      dstbase = WT1K1; }
  else if (b < 32) { src = hw2_k1; ldn = 128; t0 = b - 16; dstbase = WT2K1; }
  else if (b < 48) { src = hw1_k2; ldn = 128; t0 = b - 32; dstbase = WT1K2; }
  else if (b < 56) { src = b1_k;   ldn = 64;  t0 = b - 48; dstbase = WTM3; }
  else if (b < 64) { src = hb2_k1; ldn = 64;  t0 = b - 56; dstbase = WTM3 + 64 * 128; }
  else             { src = hw2_k2; ldn = 64;  t0 = b - 64; dstbase = WT2K2; }
  const int kt = t0 & 3, nt = t0 >> 2;
  const int tid = threadIdx.x;
  {
    const int c = tid & 31;
    for (int r = tid >> 5; r < 32; r += 8)
      t[r][c] = src[(size_t)(kt * 32 + r) * ldn + nt * 32 + c];
  }
  __syncthreads();
  {
    const int c2 = tid & 15;
    for (int n = tid >> 4; n < 32; n += 16) {
      const uint32_t v = pk2(t[2 * c2][n], t[2 * c2 + 1][n]);
      *(uint32_t*)&wt[dstbase + (nt * 32 + n) * 128 + kt * 32 + 2 * c2] = v;
    }
  }
}

// ========================= Main fused kernel =========================
// R15/R16-verified structure (RPB=16, 512 threads, full M=16 tiles, balanced
// RNG, M5 on waves 4-7 vs b2 on waves 0-3). Final build (R17 prefetch was
// neutral and is withdrawn).
__global__ __launch_bounds__(512, 4)
void alpha_mfma3(const float* __restrict__ q_vals,   // (8, 8192)
                 const float* __restrict__ states,   // (8192, 128)
                 const float* __restrict__ hw1_b1, const float* __restrict__ hw1_b2,
                 const float* __restrict__ b1_b,   const float* __restrict__ hw2_b1,
                 const float* __restrict__ hw2_b2, const float* __restrict__ hb2_b1,
                 const float* __restrict__ hb2_k2, const float* __restrict__ hb2_b2,
                 const unsigned short* __restrict__ wt,
                 float* __restrict__ out)            // (8, 8192)
{
  __shared__ unsigned short xbf[RPB * 128];     // X bf16 swz            4 KB
  __shared__ unsigned short h1bf[RPB * 128];    // relu(h1) bf16 swz     4 KB
  __shared__ unsigned short h2bf[RPB * 128];    // relu(h2) bf16 swz     4 KB
  __shared__ float w1l[RPB][132];               // |w1| f32            8.4 KB
  __shared__ float b1l[RPB][68];                //                     4.3 KB
  __shared__ float w2l[RPB][68];                //                     4.3 KB
  __shared__ float hbl[RPB][68];                //                     4.3 KB
  __shared__ float b2l[RPB];
  __shared__ float ql[RPB][N_AG];
  __shared__ float cn_l[RPB][S_SAMP][CN_STR];   // cn then |y|         9.2 KB

  const int tid  = threadIdx.x;
  const int row0 = blockIdx.x * RPB;
  const int lane = tid & 63;
  const int wv   = tid >> 6;        // wave 0..7
  const int lrow = lane & 15;       // A-row / B-col within a 16-tile
  const int lhi  = lane >> 4;       // k-group; C rows lhi*4+j (ALL 16 used)

  // ---- P0: X f32 -> bf16 swz LDS (16 rows, 512 float4 = 1/thread); q load ----
  {
    const int r = tid >> 5, k0 = (tid & 31) * 4;
    const float4 v = ld4(&states[(size_t)(row0 + r) * DST + k0]);
    const int b = (r * 256 + k0 * 2) ^ ((r & 7) << 4);
    *(uint32_t*)((char*)xbf + b)     = pk2(v.x, v.y);
    *(uint32_t*)((char*)xbf + b + 4) = pk2(v.z, v.w);
  }
  if (tid < RPB * N_AG) {
    const int rr = tid >> 3, a = tid & 7;
    ql[rr][a] = q_vals[a * TB + row0 + rr];
  }
  __syncthreads();

  // ---- RNG: one (row, sample) per thread, tid<256 = waves 0-3 (verified chain) ----
  if (tid < RPB * S_SAMP) {
    const int r  = tid >> 4;
    const int sl = tid & 15;
    const uint32_t j = (uint32_t)(row0 + r) * (uint32_t)S_SAMP + (uint32_t)sl;
    uint2 kj  = tf2x32(0u, 42u, 0u, j);       // partitionable split of key(42)
    uint2 sub = tf2x32(kj.x, kj.y, 0u, 1u);   // subkey = split(key_j)[1]
    uint32_t K[N_AG];
#pragma unroll
    for (int i = 0; i < N_AG; ++i) {
      uint2 b = tf2x32(sub.x, sub.y, 0u, (uint32_t)i);
      K[i] = b.x ^ b.y;
    }
    int posa[N_AG];
#pragma unroll
    for (int i = 0; i < N_AG; ++i) {
      int rank = 0;
#pragma unroll
      for (int m = 0; m < N_AG; ++m)
        rank += (K[m] < K[i]) || (K[m] == K[i] && m < i);
      posa[rank] = i;
    }
#pragma unroll
    for (int a = 0; a < N_AG; ++a) {
      const int pa = posa[a];
      float cs = 0.f;
#pragma unroll
      for (int a2 = 0; a2 < N_AG; ++a2)
        cs += (posa[a2] < pa) ? ql[r][a2] : 0.f;
      cn_l[r][sl][a] = cs / (float)max(pa, 1);
    }
  }

  // ===== M1: h1 = relu(X @ hw1_k1 + b) -> h1bf  (8 waves x 16 cols) =====
  {
    float4v a0 = {0.f,0.f,0.f,0.f};
    const int c = wv * 16 + lrow;
#pragma unroll
    for (int ks = 0; ks < 4; ++ks) {
      const short8v af = rdfrag(xbf, lrow, ks, lhi);
      a0 = __builtin_amdgcn_mfma_f32_16x16x32_bf16(af, gfrag(wt + WT1K1, c, ks, lhi), a0, 0, 0, 0);
    }
    const float bv = hw1_b1[c];
#pragma unroll
    for (int j = 0; j < 4; ++j)
      wrbf(h1bf, lhi * 4 + j, c, fmaxf(a0[j] + bv, 0.f));
  }

  // ===== M2: h2 = relu(X @ hw2_k1 + b) -> h2bf =====
  {
    float4v a0 = {0.f,0.f,0.f,0.f};
    const int c = wv * 16 + lrow;
#pragma unroll
    for (int ks = 0; ks < 4; ++ks) {
      const short8v af = rdfrag(xbf, lrow, ks, lhi);
      a0 = __builtin_amdgcn_mfma_f32_16x16x32_bf16(af, gfrag(wt + WT2K1, c, ks, lhi), a0, 0, 0, 0);
    }
    const float bv = hw2_b1[c];
#pragma unroll
    for (int j = 0; j < 4; ++j)
      wrbf(h2bf, lhi * 4 + j, c, fmaxf(a0[j] + bv, 0.f));
  }

  // ===== M3: cols 0..63 -> b1 = X@b1_k + b; 64..127 -> hb = relu(X@hb2_k1 + b) =====
  {
    float4v a0 = {0.f,0.f,0.f,0.f};
    const int c = wv * 16 + lrow;
#pragma unroll
    for (int ks = 0; ks < 4; ++ks) {
      const short8v af = rdfrag(xbf, lrow, ks, lhi);
      a0 = __builtin_amdgcn_mfma_f32_16x16x32_bf16(af, gfrag(wt + WTM3, c, ks, lhi), a0, 0, 0, 0);
    }
    if (c < 64) {
      const float bv = b1_b[c];
#pragma unroll
      for (int j = 0; j < 4; ++j)
        b1l[lhi * 4 + j][c] = a0[j] + bv;
    } else {
      const float bv = hb2_b1[c - 64];
#pragma unroll
      for (int j = 0; j < 4; ++j)
        hbl[lhi * 4 + j][c - 64] = fmaxf(a0[j] + bv, 0.f);
    }
  }
  __syncthreads();   // h1bf/h2bf/b1l/hbl/cn_l now visible

  // ---- b2[r] (waves 0-3) ----
  if (tid < RPB * S_SAMP) {
    const int r = tid >> 4, sl = tid & 15;
    float v = hbl[r][sl]      * hb2_k2[sl]
            + hbl[r][sl + 16] * hb2_k2[sl + 16]
            + hbl[r][sl + 32] * hb2_k2[sl + 32]
            + hbl[r][sl + 48] * hb2_k2[sl + 48];
    v += __shfl_down(v, 8, 16); v += __shfl_down(v, 4, 16);
    v += __shfl_down(v, 2, 16); v += __shfl_down(v, 1, 16);
    if (sl == 0) b2l[r] = v + hb2_b2[0];
  }

  // ===== M5: w2 = |h2 @ hw2_k2 + b| (waves 4-7; balanced vs b2 on 0-3) =====
  if (wv >= 4) {
    float4v a0 = {0.f,0.f,0.f,0.f};
    const int c = (wv - 4) * 16 + lrow;
#pragma unroll
    for (int ks = 0; ks < 4; ++ks) {
      const short8v af = rdfrag(h2bf, lrow, ks, lhi);
      a0 = __builtin_amdgcn_mfma_f32_16x16x32_bf16(af, gfrag(wt + WT2K2, c, ks, lhi), a0, 0, 0, 0);
    }
    const float bv = hw2_b2[c];
#pragma unroll
    for (int j = 0; j < 4; ++j)
      w2l[lhi * 4 + j][c] = fabsf(a0[j] + bv);
  }

  // ===== M4: w1 = |h1 @ hw1_k2 + b| -> w1l (f32), all waves =====
  {
    float4v a0 = {0.f,0.f,0.f,0.f};
    const int c = wv * 16 + lrow;
#pragma unroll
    for (int ks = 0; ks < 4; ++ks) {
      const short8v af = rdfrag(h1bf, lrow, ks, lhi);
      a0 = __builtin_amdgcn_mfma_f32_16x16x32_bf16(af, gfrag(wt + WT1K2, c, ks, lhi), a0, 0, 0, 0);
    }
    const float bv = hw1_b2[c];
#pragma unroll
    for (int j = 0; j < 4; ++j)
      w1l[lhi * 4 + j][c] = fabsf(a0[j] + bv);
  }
  __syncthreads();   // w1l/w2l/b2l visible

  // ===== Main: thread = (r in 16, sl in 16, agent-half in 2); all 512 active =====
  {
    const int sl  = tid & 15;
    const int r   = (tid >> 4) & 15;
    const int a0i = (tid >> 8) * 4;   // agents a0i..a0i+3
    float cn[4], qv[4], y[4];
#pragma unroll
    for (int jj = 0; jj < 4; ++jj) {
      cn[jj] = cn_l[r][sl][a0i + jj];
      qv[jj] = ql[r][a0i + jj];
      y[jj]  = 0.f;
    }
#pragma unroll 4
    for (int e = 0; e < E_DIM; e += 4) {
      const float4 wa  = ld4(&w1l[r][e]);
      const float4 wb  = ld4(&w1l[r][64 + e]);
      const float4 bb  = ld4(&b1l[r][e]);
      const float4 w2v = ld4(&w2l[r][e]);
#pragma unroll
      for (int jj = 0; jj < 4; ++jj) {
        float h;
        h = fmaf(cn[jj], wa.x, fmaf(qv[jj], wb.x, bb.x));
        y[jj] = fmaf((h > 0.f) ? h : (__expf(h) - 1.f), w2v.x, y[jj]);
        h = fmaf(cn[jj], wa.y, fmaf(qv[jj], wb.y, bb.y));
        y[jj] = fmaf((h > 0.f) ? h : (__expf(h) - 1.f), w2v.y, y[jj]);
        h = fmaf(cn[jj], wa.z, fmaf(qv[jj], wb.z, bb.z));
        y[jj] = fmaf((h > 0.f) ? h : (__expf(h) - 1.f), w2v.z, y[jj]);
        h = fmaf(cn[jj], wa.w, fmaf(qv[jj], wb.w, bb.w));
        y[jj] = fmaf((h > 0.f) ? h : (__expf(h) - 1.f), w2v.w, y[jj]);
      }
    }
    const float b2v = b2l[r];
#pragma unroll
    for (int jj = 0; jj < 4; ++jj)
      cn_l[r][sl][a0i + jj] = fabsf(y[jj] + b2v);   // own slots only
  }
  __syncthreads();

  // ---- Reduce over samples; rr = tid&15 so 16 consecutive rows coalesce ----
  if (tid < RPB * N_AG) {
    const int rr = tid & 15, a = tid >> 4;
    float acc = 0.f;
#pragma unroll
    for (int ss = 0; ss < S_SAMP; ++ss) acc += cn_l[rr][ss][a];
    out[a * TB + row0 + rr] = acc * (1.0f / (float)S_SAMP);
  }
}

// ============ Fallback (R4-structure, proven): used only if ws too small ============
#define FB_RPB 16
#define FB_H_PAD 132
#define FB_E_PAD 68
__global__ __launch_bounds__(256)
void alpha_fused2(const float* __restrict__ q_vals, const float* __restrict__ states,
                  const float* __restrict__ hw1_k1, const float* __restrict__ hw1_b1,
                  const float* __restrict__ hw1_k2, const float* __restrict__ hw1_b2,
                  const float* __restrict__ b1_k,   const float* __restrict__ b1_b,
                  const float* __restrict__ hw2_k1, const float* __restrict__ hw2_b1,
                  const float* __restrict__ hw2_k2, const float* __restrict__ hw2_b2,
                  const float* __restrict__ hb2_k1, const float* __restrict__ hb2_b1,
                  const float* __restrict__ hb2_k2, const float* __restrict__ hb2_b2,
                  float* __restrict__ out)
{
  __shared__ float s_lds[FB_RPB][DST];
  __shared__ float scratch[FB_RPB][FB_H_PAD];
  __shared__ float scratch2[FB_RPB][FB_E_PAD];
  __shared__ float w1l[FB_RPB][FB_H_PAD];
  __shared__ float b1l[FB_RPB][FB_E_PAD];
  __shared__ float w2l[FB_RPB][FB_E_PAD];
  __shared__ float b2l[FB_RPB];
  __shared__ float qlf[FB_RPB][N_AG];
  __shared__ float cnred[FB_RPB][S_SAMP][N_AG];
  const int tid = threadIdx.x;
  const int row0 = blockIdx.x * FB_RPB;
  const int r = tid >> 4, sl = tid & 15;
  {
    const float4* src = reinterpret_cast<const float4*>(states + (size_t)row0 * DST);
    reinterpret_cast<float4*>(&s_lds[0][0])[tid]       = src[tid];
    reinterpret_cast<float4*>(&s_lds[0][0])[tid + 256] = src[tid + 256];
  }
  if (tid < FB_RPB * N_AG) {
    const int rr = tid >> 3, a = tid & 7;
    qlf[rr][a] = q_vals[a * TB + row0 + rr];
  }
  __syncthreads();
  {
    const uint32_t j = (uint32_t)(row0 + r) * (uint32_t)S_SAMP + (uint32_t)sl;
    uint2 kj = tf2x32(0u, 42u, 0u, j);
    uint2 sub = tf2x32(kj.x, kj.y, 0u, 1u);
    uint32_t K[N_AG];
#pragma unroll
    for (int i = 0; i < N_AG; ++i) { uint2 b = tf2x32(sub.x, sub.y, 0u, (uint32_t)i); K[i] = b.x ^ b.y; }
    int posa[N_AG];
#pragma unroll
    for (int i = 0; i < N_AG; ++i) {
      int rank = 0;
#pragma unroll
      for (int m = 0; m < N_AG; ++m) rank += (K[m] < K[i]) || (K[m] == K[i] && m < i);
      posa[rank] = i;
    }
#pragma unroll
    for (int a = 0; a < N_AG; ++a) {
      const int pa = posa[a];
      float cs = 0.f;
#pragma unroll
      for (int a2 = 0; a2 < N_AG; ++a2) cs += (posa[a2] < pa) ? qlf[r][a2] : 0.f;
      cnred[r][sl][a] = cs / (float)max(pa, 1);
    }
  }
  {
    int c = tid & 127, rg = tid >> 7;
    float a0=0.f,a1=0.f,a2=0.f,a3=0.f,a4=0.f,a5=0.f,a6=0.f,a7=0.f;
#pragma unroll 2
    for (int k = 0; k < DST; ++k) {
      float wv = hw1_k1[k * 128 + c];
      a0 += s_lds[rg*8+0][k]*wv; a1 += s_lds[rg*8+1][k]*wv;
      a2 += s_lds[rg*8+2][k]*wv; a3 += s_lds[rg*8+3][k]*wv;
      a4 += s_lds[rg*8+4][k]*wv; a5 += s_lds[rg*8+5][k]*wv;
      a6 += s_lds[rg*8+6][k]*wv; a7 += s_lds[rg*8+7][k]*wv;
    }
    float b = hw1_b1[c];
    scratch[rg*8+0][c]=fmaxf(a0+b,0.f); scratch[rg*8+1][c]=fmaxf(a1+b,0.f);
    scratch[rg*8+2][c]=fmaxf(a2+b,0.f); scratch[rg*8+3][c]=fmaxf(a3+b,0.f);
    scratch[rg*8+4][c]=fmaxf(a4+b,0.f); scratch[rg*8+5][c]=fmaxf(a5+b,0.f);
    scratch[rg*8+6][c]=fmaxf(a6+b,0.f); scratch[rg*8+7][c]=fmaxf(a7+b,0.f);
  }
  {
    int c = tid & 63, rg = tid >> 6;
    float a0=0.f,a1=0.f,a2=0.f,a3=0.f;
#pragma unroll 2
    for (int k = 0; k < DST; ++k) {
      float wv = b1_k[k * 64 + c];
      a0 += s_lds[rg*4+0][k]*wv; a1 += s_lds[rg*4+1][k]*wv;
      a2 += s_lds[rg*4+2][k]*wv; a3 += s_lds[rg*4+3][k]*wv;
    }
    float b = b1_b[c];
    b1l[rg*4+0][c]=a0+b; b1l[rg*4+1][c]=a1+b; b1l[rg*4+2][c]=a2+b; b1l[rg*4+3][c]=a3+b;
  }
  __syncthreads();
  {
    int c = tid & 127, rg = tid >> 7;
    float a0=0.f,a1=0.f,a2=0.f,a3=0.f,a4=0.f,a5=0.f,a6=0.f,a7=0.f;
#pragma unroll 2
    for (int k = 0; k < DST; ++k) {
      float wv = hw1_k2[k * 128 + c];
      a0 += scratch[rg*8+0][k]*wv; a1 += scratch[rg*8+1][k]*wv;
      a2 += scratch[rg*8+2][k]*wv; a3 += scratch[rg*8+3][k]*wv;
      a4 += scratch[rg*8+4][k]*wv; a5 += scratch[rg*8+5][k]*wv;
      a6 += scratch[rg*8+6][k]*wv; a7 += scratch[rg*8+7][k]*wv;
    }
    float b = hw1_b2[c];
    w1l[rg*8+0][c]=fabsf(a0+b); w1l[rg*8+1][c]=fabsf(a1+b);
    w1l[rg*8+2][c]=fabsf(a2+b); w1l[rg*8+3][c]=fabsf(a3+b);
    w1l[rg*8+4][c]=fabsf(a4+b); w1l[rg*8+5][c]=fabsf(a5+b);
    w1l[rg*8+6][c]=fabsf(a6+b); w1l[rg*8+7][c]=fabsf(a7+b);
  }
  {
    int c = tid & 63, rg = tid >> 6;
    float a0=0.f,a1=0.f,a2=0.f,a3=0.f;
#pragma unroll 2
    for (int k = 0; k < DST; ++k) {
      float wv = hb2_k1[k * 64 + c];
      a0 += s_lds[rg*4+0][k]*wv; a1 += s_lds[rg*4+1][k]*wv;
      a2 += s_lds[rg*4+2][k]*wv; a3 += s_lds[rg*4+3][k]*wv;
    }
    float b = hb2_b1[c];
    scratch2[rg*4+0][c]=fmaxf(a0+b,0.f); scratch2[rg*4+1][c]=fmaxf(a1+b,0.f);
    scratch2[rg*4+2][c]=fmaxf(a2+b,0.f); scratch2[rg*4+3][c]=fmaxf(a3+b,0.f);
  }
  __syncthreads();
  {
    int c = tid & 127, rg = tid >> 7;
    float a0=0.f,a1=0.f,a2=0.f,a3=0.f,a4=0.f,a5=0.f,a6=0.f,a7=0.f;
#pragma unroll 2
    for (int k = 0; k < DST; ++k) {
      float wv = hw2_k1[k * 128 + c];
      a0 += s_lds[rg*8+0][k]*wv; a1 += s_lds[rg*8+1][k]*wv;
      a2 += s_lds[rg*8+2][k]*wv; a3 += s_lds[rg*8+3][k]*wv;
      a4 += s_lds[rg*8+4][k]*wv; a5 += s_lds[rg*8+5][k]*wv;
      a6 += s_lds[rg*8+6][k]*wv; a7 += s_lds[rg*8+7][k]*wv;
    }
    float b = hw2_b1[c];
    scratch[rg*8+0][c]=fmaxf(a0+b,0.f); scratch[rg*8+1][c]=fmaxf(a1+b,0.f);
    scratch[rg*8+2][c]=fmaxf(a2+b,0.f); scratch[rg*8+3][c]=fmaxf(a3+b,0.f);
    scratch[rg*8+4][c]=fmaxf(a4+b,0.f); scratch[rg*8+5][c]=fmaxf(a5+b,0.f);
    scratch[rg*8+6][c]=fmaxf(a6+b,0.f); scratch[rg*8+7][c]=fmaxf(a7+b,0.f);
  }
  if (tid < FB_RPB * S_SAMP) {
    float v = scratch2[r][sl]      * hb2_k2[sl]
            + scratch2[r][sl + 16] * hb2_k2[sl + 16]
            + scratch2[r][sl + 32] * hb2_k2[sl + 32]
            + scratch2[r][sl + 48] * hb2_k2[sl + 48];
    v += __shfl_down(v, 8, 16); v += __shfl_down(v, 4, 16);
    v += __shfl_down(v, 2, 16); v += __shfl_down(v, 1, 16);
    if (sl == 0) b2l[r] = v + hb2_b2[0];
  }
  __syncthreads();
  {
    int c = tid & 63, rg = tid >> 6;
    float a0=0.f,a1=0.f,a2=0.f,a3=0.f;
#pragma unroll 2
    for (int k = 0; k < DST; ++k) {
      float wv = hw2_k2[k * 64 + c];
      a0 += scratch[rg*4+0][k]*wv; a1 += scratch[rg*4+1][k]*wv;
      a2 += scratch[rg*4+2][k]*wv; a3 += scratch[rg*4+3][k]*wv;
    }
    float b = hw2_b2[c];
    w2l[rg*4+0][c]=fabsf(a0+b); w2l[rg*4+1][c]=fabsf(a1+b);
    w2l[rg*4+2][c]=fabsf(a2+b); w2l[rg*4+3][c]=fabsf(a3+b);
  }
  __syncthreads();
  {
    float cn[N_AG], qv[N_AG], y[N_AG];
#pragma unroll
    for (int a = 0; a < N_AG; ++a) { cn[a]=cnred[r][sl][a]; qv[a]=qlf[r][a]; y[a]=0.f; }
#pragma unroll 4
    for (int e = 0; e < E_DIM; e += 4) {
      const float4 wa  = ld4(&w1l[r][e]);
      const float4 wb  = ld4(&w1l[r][64 + e]);
      const float4 bb  = ld4(&b1l[r][e]);
      const float4 w2v = ld4(&w2l[r][e]);
#pragma unroll
      for (int a = 0; a < N_AG; ++a) {
        float h;
        h = fmaf(cn[a], wa.x, fmaf(qv[a], wb.x, bb.x));
        y[a] = fmaf((h > 0.f) ? h : (__expf(h) - 1.f), w2v.x, y[a]);
        h = fmaf(cn[a], wa.y, fmaf(qv[a], wb.y, bb.y));
        y[a] = fmaf((h > 0.f) ? h : (__expf(h) - 1.f), w2v.y, y[a]);
        h = fmaf(cn[a], wa.z, fmaf(qv[a], wb.z, bb.z));
        y[a] = fmaf((h > 0.f) ? h : (__expf(h) - 1.f), w2v.z, y[a]);
        h = fmaf(cn[a], wa.w, fmaf(qv[a], wb.w, bb.w));
        y[a] = fmaf((h > 0.f) ? h : (__expf(h) - 1.f), w2v.w, y[a]);
      }
    }
    const float b2v = b2l[r];
#pragma unroll
    for (int a = 0; a < N_AG; ++a) cnred[r][sl][a] = fabsf(y[a] + b2v);
  }
  __syncthreads();
  if (tid < FB_RPB * N_AG) {
    const int a = tid >> 4, rr = tid & 15;
    float acc = 0.f;
#pragma unroll
    for (int ss = 0; ss < S_SAMP; ++ss) acc += cnred[rr][ss][a];
    out[a * TB + row0 + rr] = acc * (1.0f / (float)S_SAMP);
  }
}

extern "C" void kernel_launch(void* const* d_in, const int* in_sizes, int n_in,
                              void* d_out, int out_size, void* d_ws, size_t ws_size,
                              hipStream_t stream) {
  const float* q_vals = (const float*)d_in[0];
  const float* states = (const float*)d_in[1];
  const float* hw1_k1 = (const float*)d_in[2];
  const float* hw1_b1 = (const float*)d_in[3];
  const float* hw1_k2 = (const float*)d_in[4];
  const float* hw1_b2 = (const float*)d_in[5];
  const float* b1_k   = (const float*)d_in[6];
  const float* b1_b   = (const float*)d_in[7];
  const float* hw2_k1 = (const float*)d_in[8];
  const float* hw2_b1 = (const float*)d_in[9];
  const float* hw2_k2 = (const float*)d_in[10];
  const float* hw2_b2 = (const float*)d_in[11];
  const float* hb2_k1 = (const float*)d_in[12];
  const float* hb2_b1 = (const float*)d_in[13];
  const float* hb2_k2 = (const float*)d_in[14];
  const float* hb2_b2 = (const float*)d_in[15];
  float* out = (float*)d_out;

  const size_t need = (size_t)WT_ELEMS * sizeof(unsigned short);
  if (ws_size >= need) {
    unsigned short* wt = (unsigned short*)d_ws;
    wt_transpose<<<dim3(72), 256, 0, stream>>>(
        hw1_k1, hw2_k1, hw1_k2, b1_k, hb2_k1, hw2_k2, wt);
    alpha_mfma3<<<dim3(TB / RPB), 512, 0, stream>>>(
        q_vals, states, hw1_b1, hw1_b2, b1_b, hw2_b1, hw2_b2, hb2_b1,
        hb2_k2, hb2_b2, wt, out);
  } else {
    alpha_fused2<<<dim3(TB / FB_RPB), 256, 0, stream>>>(
        q_vals, states, hw1_k1, hw1_b1, hw1_k2, hw1_b2, b1_k, b1_b,
        hw2_k1, hw2_b1, hw2_k2, hw2_b2, hb2_k1, hb2_b1, hb2_k2, hb2_b2, out);
  }
}